// Round 1
// baseline (1342.920 us; speedup 1.0000x reference)
//
#include <hip/hip_runtime.h>
#include <hip/hip_bf16.h>

#define BB 16
#define SS 8192
#define HH 512
#define PP 32

// ---------------------------------------------------------------------------
// K1: scores[b][p][s] = sum_h probes[p][h] * x[b][s][h]
// grid (S/32, B), block 256. Thread = (probe p = t&31, row-quad rq = t>>5).
// Probes staged in LDS as float4 chunks, XOR-swizzled by (p&7) so that a
// wave's 32 p-lanes hit 8 distinct bank groups instead of 1.
// ---------------------------------------------------------------------------
__global__ __launch_bounds__(256, 2) void k_scores(
    const float* __restrict__ x, const float* __restrict__ probes,
    float* __restrict__ scores) {
  __shared__ float4 pr[PP * 128];  // 32 probes x 128 float4 = 64 KB
  const int t = threadIdx.x;
  const int b = blockIdx.y;
  const int s0 = blockIdx.x * 32;

  const float4* src = (const float4*)probes;  // 4096 float4
#pragma unroll
  for (int i = t; i < 4096; i += 256) {
    int pp = i >> 7, q = i & 127;
    pr[(pp << 7) | (q ^ (pp & 7))] = src[i];
  }
  __syncthreads();

  const int p = t & 31, rq = t >> 5;
  const float4* xr4 = (const float4*)(x + ((size_t)b * SS + s0 + rq * 4) * HH);
  const float4* prp = pr + (p << 7);
  const int sw = p & 7;

  float acc0 = 0.f, acc1 = 0.f, acc2 = 0.f, acc3 = 0.f;
#pragma unroll 4
  for (int q = 0; q < 128; ++q) {
    float4 pv = prp[q ^ sw];
    float4 r0 = xr4[q];
    float4 r1 = xr4[128 + q];
    float4 r2 = xr4[256 + q];
    float4 r3 = xr4[384 + q];
    acc0 = fmaf(pv.x, r0.x, fmaf(pv.y, r0.y, fmaf(pv.z, r0.z, fmaf(pv.w, r0.w, acc0))));
    acc1 = fmaf(pv.x, r1.x, fmaf(pv.y, r1.y, fmaf(pv.z, r1.z, fmaf(pv.w, r1.w, acc1))));
    acc2 = fmaf(pv.x, r2.x, fmaf(pv.y, r2.y, fmaf(pv.z, r2.z, fmaf(pv.w, r2.w, acc2))));
    acc3 = fmaf(pv.x, r3.x, fmaf(pv.y, r3.y, fmaf(pv.z, r3.z, fmaf(pv.w, r3.w, acc3))));
  }

  float* sc = scores + ((size_t)(b * PP + p)) * SS + s0 + rq * 4;
  sc[0] = acc0; sc[1] = acc1; sc[2] = acc2; sc[3] = acc3;
}

// ---------------------------------------------------------------------------
// K2: per (b,p): M = max_s score, invl = 1/sum_s exp(score - M)
// grid (B*P), block 256. 8 float4 per thread held in registers.
// ---------------------------------------------------------------------------
__global__ __launch_bounds__(256) void k_stats(
    const float* __restrict__ scores, float* __restrict__ Mv,
    float* __restrict__ invl) {
  const int bp = blockIdx.x;
  const int t = threadIdx.x;
  const float4* sc = (const float4*)(scores + (size_t)bp * SS);  // 2048 f4

  float4 v[8];
  float m = -1e30f;
#pragma unroll
  for (int i = 0; i < 8; ++i) {
    v[i] = sc[t + 256 * i];
    m = fmaxf(m, fmaxf(fmaxf(v[i].x, v[i].y), fmaxf(v[i].z, v[i].w)));
  }
#pragma unroll
  for (int o = 32; o > 0; o >>= 1) m = fmaxf(m, __shfl_xor(m, o));

  __shared__ float wred[4];
  if ((t & 63) == 0) wred[t >> 6] = m;
  __syncthreads();
  m = fmaxf(fmaxf(wred[0], wred[1]), fmaxf(wred[2], wred[3]));
  __syncthreads();

  float s = 0.f;
#pragma unroll
  for (int i = 0; i < 8; ++i)
    s += __expf(v[i].x - m) + __expf(v[i].y - m) +
         __expf(v[i].z - m) + __expf(v[i].w - m);
#pragma unroll
  for (int o = 32; o > 0; o >>= 1) s += __shfl_xor(s, o);
  if ((t & 63) == 0) wred[t >> 6] = s;
  __syncthreads();
  if (t == 0) {
    s = wred[0] + wred[1] + wred[2] + wred[3];
    Mv[bp] = m;
    invl[bp] = 1.0f / s;
  }
}

// ---------------------------------------------------------------------------
// K3: ctx[b][p][h] += sum_s softmax_w[b][p][s] * x[b][s][h]
// grid (S/256, B), block 256. Thread = (probe-quad pq = t&7, h-slice hs=t>>3).
// 16-row chunks staged in LDS; weights computed inline into padded LDS.
// acc[4][16] in registers; epilogue atomics into zeroed d_out.
// ---------------------------------------------------------------------------
__global__ __launch_bounds__(256, 4) void k_ctx(
    const float* __restrict__ x, const float* __restrict__ scores,
    const float* __restrict__ Mv, const float* __restrict__ invl,
    float* __restrict__ out) {
  __shared__ float rows[16 * HH];  // 32 KB
  __shared__ float w[PP][17];      // padded -> conflict-free
  const int t = threadIdx.x;
  const int b = blockIdx.y;
  const int s0 = blockIdx.x * 256;
  const int pq = t & 7, hs = t >> 3;

  float acc[4][16];
#pragma unroll
  for (int jj = 0; jj < 4; ++jj)
#pragma unroll
    for (int k = 0; k < 16; ++k) acc[jj][k] = 0.f;

  for (int c = 0; c < 16; ++c) {
    __syncthreads();
    // stage 16 rows (8192 floats)
    const float4* src = (const float4*)(x + ((size_t)b * SS + s0 + c * 16) * HH);
    float4* dst = (float4*)rows;
#pragma unroll
    for (int i = t; i < 2048; i += 256) dst[i] = src[i];
    // stage softmax weights for these 16 rows
    if (t < 128) {
      int p_i = t >> 2, j4 = (t & 3) * 4;
      const float* scp = scores + (size_t)(b * PP + p_i) * SS + s0 + c * 16 + j4;
      float mm = Mv[b * PP + p_i];
      float ll = invl[b * PP + p_i];
      float4 sv = *(const float4*)scp;
      w[p_i][j4 + 0] = __expf(sv.x - mm) * ll;
      w[p_i][j4 + 1] = __expf(sv.y - mm) * ll;
      w[p_i][j4 + 2] = __expf(sv.z - mm) * ll;
      w[p_i][j4 + 3] = __expf(sv.w - mm) * ll;
    }
    __syncthreads();

#pragma unroll 2
    for (int j = 0; j < 16; ++j) {
      const float4* rj = (const float4*)&rows[j * HH + hs * 16];
      float4 r0 = rj[0], r1 = rj[1], r2 = rj[2], r3 = rj[3];
      float rr[16] = {r0.x, r0.y, r0.z, r0.w, r1.x, r1.y, r1.z, r1.w,
                      r2.x, r2.y, r2.z, r2.w, r3.x, r3.y, r3.z, r3.w};
      float wj[4];
#pragma unroll
      for (int jj = 0; jj < 4; ++jj) wj[jj] = w[pq * 4 + jj][j];
#pragma unroll
      for (int jj = 0; jj < 4; ++jj)
#pragma unroll
        for (int k = 0; k < 16; ++k)
          acc[jj][k] = fmaf(wj[jj], rr[k], acc[jj][k]);
    }
  }

#pragma unroll
  for (int jj = 0; jj < 4; ++jj) {
    float* op = out + (size_t)(b * PP + pq * 4 + jj) * HH + hs * 16;
#pragma unroll
    for (int k = 0; k < 16; ++k) unsafeAtomicAdd(&op[k], acc[jj][k]);
  }
}

extern "C" void kernel_launch(void* const* d_in, const int* in_sizes, int n_in,
                              void* d_out, int out_size, void* d_ws, size_t ws_size,
                              hipStream_t stream) {
  const float* x = (const float*)d_in[0];       // [B,S,H] f32
  const float* probes = (const float*)d_in[1];  // [P,H]  f32
  float* out = (float*)d_out;                   // [B,P*H] f32

  float* scores = (float*)d_ws;                       // B*P*S floats = 16.8 MB
  float* Mv = scores + (size_t)BB * PP * SS;          // B*P
  float* invl = Mv + BB * PP;                         // B*P

  hipMemsetAsync(d_out, 0, sizeof(float) * BB * PP * HH, stream);
  k_scores<<<dim3(SS / 32, BB), 256, 0, stream>>>(x, probes, scores);
  k_stats<<<dim3(BB * PP), 256, 0, stream>>>(scores, Mv, invl);
  k_ctx<<<dim3(SS / 256, BB), 256, 0, stream>>>(x, scores, Mv, invl, out);
}

// Round 2
// 838.169 us; speedup vs baseline: 1.6022x; 1.6022x over previous
//
#include <hip/hip_runtime.h>
#include <hip/hip_bf16.h>

#define BB 16
#define SS 8192
#define HH 512
#define PP 32

typedef __attribute__((ext_vector_type(8))) short short8;
typedef __attribute__((ext_vector_type(4))) float f32x4;

// ---- bf16 split helpers: x ~= hi + lo, combined precision ~2^-16 relative --
__device__ inline short bf16_rne(float x) {
  union { float f; unsigned u; } v; v.f = x;
  unsigned r = v.u + 0x7FFFu + ((v.u >> 16) & 1u);
  return (short)(r >> 16);
}
__device__ inline void bf16_split(float x, short& h, short& l) {
  union { float f; unsigned u; } v; v.f = x;
  h = (short)(v.u >> 16);  // truncated hi
  union { unsigned u; float f; } hv; hv.u = ((unsigned)(unsigned short)h) << 16;
  l = bf16_rne(x - hv.f);  // residual
}

// ---------------------------------------------------------------------------
// K0: pack probes [32][512] f32 into A-fragment layout (hi & lo bf16).
// Slot q = (mt*16 + kc)*64 + lane holds 8 bf16: probes[mt*16 + (lane&15)]
//                                              [kc*32 + (lane>>4)*8 + j]
// ---------------------------------------------------------------------------
__global__ void k_prep(const float* __restrict__ probes,
                       short* __restrict__ Ah, short* __restrict__ Al) {
  int t = threadIdx.x;
  for (int q = t; q < 2048; q += 256) {
    int lane = q & 63, kc = (q >> 6) & 15, mt = q >> 10;
    int p = mt * 16 + (lane & 15);
    int h0 = kc * 32 + (lane >> 4) * 8;
#pragma unroll
    for (int j = 0; j < 8; ++j) {
      short h, l;
      bf16_split(probes[p * 512 + h0 + j], h, l);
      Ah[q * 8 + j] = h;
      Al[q * 8 + j] = l;
    }
  }
}

// ---------------------------------------------------------------------------
// K1: scores[b][p][s] = probes[p][:] . x[b][s][:]  via 3-term split-bf16 MFMA.
// grid (S/128, B), block 256 (4 waves). Wave w owns n-rows s_base..+31.
// B-frags converted from global f32 in-register; A-frags from packed ws (L2).
// ---------------------------------------------------------------------------
__global__ __launch_bounds__(256) void k_scores_mfma(
    const float* __restrict__ x, const short* __restrict__ Ah,
    const short* __restrict__ Al, float* __restrict__ scores) {
  const int t = threadIdx.x;
  const int lane = t & 63, w = t >> 6;
  const int b = blockIdx.y;
  const int s_base = blockIdx.x * 128 + w * 32;
  const int r0 = lane & 15, koff = (lane >> 4) * 8;

  f32x4 acc[2][2];
#pragma unroll
  for (int i = 0; i < 2; ++i)
#pragma unroll
    for (int j = 0; j < 2; ++j) acc[i][j] = (f32x4){0.f, 0.f, 0.f, 0.f};

  const float* xb0 = x + ((size_t)(b * SS) + s_base + r0) * HH + koff;

  for (int kc = 0; kc < 16; ++kc) {
    short8 ah0 = *(const short8*)(Ah + ((size_t)(kc)*64 + lane) * 8);
    short8 ah1 = *(const short8*)(Ah + ((size_t)(16 + kc) * 64 + lane) * 8);
    short8 al0 = *(const short8*)(Al + ((size_t)(kc)*64 + lane) * 8);
    short8 al1 = *(const short8*)(Al + ((size_t)(16 + kc) * 64 + lane) * 8);

#pragma unroll
    for (int nt = 0; nt < 2; ++nt) {
      const float* xp = xb0 + (size_t)(nt * 16) * HH + kc * 32;
      f32x4 xa = *(const f32x4*)xp;
      f32x4 xc = *(const f32x4*)(xp + 4);
      short8 bh, bl;
      float xv[8] = {xa.x, xa.y, xa.z, xa.w, xc.x, xc.y, xc.z, xc.w};
#pragma unroll
      for (int j = 0; j < 8; ++j) {
        short h, l;
        bf16_split(xv[j], h, l);
        bh[j] = h; bl[j] = l;
      }
      acc[0][nt] = __builtin_amdgcn_mfma_f32_16x16x32_bf16(ah0, bh, acc[0][nt], 0, 0, 0);
      acc[0][nt] = __builtin_amdgcn_mfma_f32_16x16x32_bf16(ah0, bl, acc[0][nt], 0, 0, 0);
      acc[0][nt] = __builtin_amdgcn_mfma_f32_16x16x32_bf16(al0, bh, acc[0][nt], 0, 0, 0);
      acc[1][nt] = __builtin_amdgcn_mfma_f32_16x16x32_bf16(ah1, bh, acc[1][nt], 0, 0, 0);
      acc[1][nt] = __builtin_amdgcn_mfma_f32_16x16x32_bf16(ah1, bl, acc[1][nt], 0, 0, 0);
      acc[1][nt] = __builtin_amdgcn_mfma_f32_16x16x32_bf16(al1, bh, acc[1][nt], 0, 0, 0);
    }
  }

  // C/D: col(n=s)=lane&15, row(m=p)=(lane>>4)*4+reg   [m89-verified mapping]
#pragma unroll
  for (int mt = 0; mt < 2; ++mt)
#pragma unroll
    for (int nt = 0; nt < 2; ++nt) {
      int s = s_base + nt * 16 + (lane & 15);
#pragma unroll
      for (int r = 0; r < 4; ++r) {
        int p = mt * 16 + (lane >> 4) * 4 + r;
        scores[(size_t)(b * PP + p) * SS + s] = acc[mt][nt][r];
      }
    }
}

// ---------------------------------------------------------------------------
// K2: per (b,p): M = max_s score, invl = 1/sum_s exp(score - M)
// ---------------------------------------------------------------------------
__global__ __launch_bounds__(256) void k_stats(
    const float* __restrict__ scores, float* __restrict__ Mv,
    float* __restrict__ invl) {
  const int bp = blockIdx.x;
  const int t = threadIdx.x;
  const f32x4* sc = (const f32x4*)(scores + (size_t)bp * SS);

  f32x4 v[8];
  float m = -1e30f;
#pragma unroll
  for (int i = 0; i < 8; ++i) {
    v[i] = sc[t + 256 * i];
    m = fmaxf(m, fmaxf(fmaxf(v[i].x, v[i].y), fmaxf(v[i].z, v[i].w)));
  }
#pragma unroll
  for (int o = 32; o > 0; o >>= 1) m = fmaxf(m, __shfl_xor(m, o));

  __shared__ float wred[4];
  if ((t & 63) == 0) wred[t >> 6] = m;
  __syncthreads();
  m = fmaxf(fmaxf(wred[0], wred[1]), fmaxf(wred[2], wred[3]));
  __syncthreads();

  float s = 0.f;
#pragma unroll
  for (int i = 0; i < 8; ++i)
    s += __expf(v[i].x - m) + __expf(v[i].y - m) +
         __expf(v[i].z - m) + __expf(v[i].w - m);
#pragma unroll
  for (int o = 32; o > 0; o >>= 1) s += __shfl_xor(s, o);
  if ((t & 63) == 0) wred[t >> 6] = s;
  __syncthreads();
  if (t == 0) {
    s = wred[0] + wred[1] + wred[2] + wred[3];
    Mv[bp] = m;
    invl[bp] = 1.0f / s;
  }
}

// ---------------------------------------------------------------------------
// K3: partial[b][p][h] over a 512-s chunk & 128-h quarter. No atomics.
// grid (16 s-chunks, 4 h-quarters, B), block 256. Thread = 1 p x 16 h.
// x float4 loads shared by 8 lanes (512B new data / wave-instr-group);
// w staged per 128-s subchunk in padded LDS (broadcast, conflict-free).
// ---------------------------------------------------------------------------
__global__ __launch_bounds__(256) void k_ctx2(
    const float* __restrict__ x, const float* __restrict__ scores,
    const float* __restrict__ Mv, const float* __restrict__ invl,
    float* __restrict__ part) {
  __shared__ float wlds[PP][132];  // pad 132: lanes' 8 distinct p -> 8 banks
  const int t = threadIdx.x;
  const int sc = blockIdx.x, hq = blockIdx.y, b = blockIdx.z;
  const int s0 = sc * 512;
  const int p = t >> 3, hs = t & 7;

  float acc[16];
#pragma unroll
  for (int k = 0; k < 16; ++k) acc[k] = 0.f;

  const float* xbase = x + ((size_t)b * SS + s0) * HH + hq * 128 + hs * 16;

  for (int c = 0; c < 4; ++c) {
    __syncthreads();
    // stage w[32][128] for s in [s0+c*128, +128)
#pragma unroll
    for (int r = 0; r < 16; ++r) {
      int i = t + 256 * r;
      int p_i = i >> 7, j = i & 127;
      float sv = scores[(size_t)(b * PP + p_i) * SS + s0 + c * 128 + j];
      wlds[p_i][j] = __expf(sv - Mv[b * PP + p_i]) * invl[b * PP + p_i];
    }
    __syncthreads();

    const float* wrow = &wlds[p][0];
    const f32x4* xr = (const f32x4*)(xbase + (size_t)(c * 128) * HH);
#pragma unroll 4
    for (int j = 0; j < 128; ++j) {
      f32x4 x0 = xr[(size_t)j * 128 + 0];
      f32x4 x1 = xr[(size_t)j * 128 + 1];
      f32x4 x2 = xr[(size_t)j * 128 + 2];
      f32x4 x3 = xr[(size_t)j * 128 + 3];
      float wj = wrow[j];
      acc[0] = fmaf(wj, x0.x, acc[0]);   acc[1] = fmaf(wj, x0.y, acc[1]);
      acc[2] = fmaf(wj, x0.z, acc[2]);   acc[3] = fmaf(wj, x0.w, acc[3]);
      acc[4] = fmaf(wj, x1.x, acc[4]);   acc[5] = fmaf(wj, x1.y, acc[5]);
      acc[6] = fmaf(wj, x1.z, acc[6]);   acc[7] = fmaf(wj, x1.w, acc[7]);
      acc[8] = fmaf(wj, x2.x, acc[8]);   acc[9] = fmaf(wj, x2.y, acc[9]);
      acc[10] = fmaf(wj, x2.z, acc[10]); acc[11] = fmaf(wj, x2.w, acc[11]);
      acc[12] = fmaf(wj, x3.x, acc[12]); acc[13] = fmaf(wj, x3.y, acc[13]);
      acc[14] = fmaf(wj, x3.z, acc[14]); acc[15] = fmaf(wj, x3.w, acc[15]);
    }
  }

  float* op = part + (((size_t)sc * BB + b) * PP + p) * HH + hq * 128 + hs * 16;
#pragma unroll
  for (int k = 0; k < 4; ++k)
    *(f32x4*)(op + k * 4) = (f32x4){acc[k * 4], acc[k * 4 + 1],
                                    acc[k * 4 + 2], acc[k * 4 + 3]};
}

// ---------------------------------------------------------------------------
// K4: out = sum over 16 s-chunk partials
// ---------------------------------------------------------------------------
__global__ __launch_bounds__(256) void k_reduce(const float* __restrict__ part,
                                               float* __restrict__ out) {
  int i = blockIdx.x * 256 + threadIdx.x;  // 262144 total
  float s = 0.f;
#pragma unroll
  for (int c = 0; c < 16; ++c) s += part[(size_t)c * (BB * PP * HH) + i];
  out[i] = s;
}

extern "C" void kernel_launch(void* const* d_in, const int* in_sizes, int n_in,
                              void* d_out, int out_size, void* d_ws, size_t ws_size,
                              hipStream_t stream) {
  const float* x = (const float*)d_in[0];       // [B,S,H] f32
  const float* probes = (const float*)d_in[1];  // [P,H]  f32
  float* out = (float*)d_out;                   // [B,P*H] f32

  float* scores = (float*)d_ws;                        // 16 MB
  float* Mv = scores + (size_t)BB * PP * SS;           // 512
  float* invl = Mv + BB * PP;                          // 512
  short* Ah = (short*)(invl + BB * PP);                // 32 KB
  short* Al = Ah + PP * HH;                            // 32 KB
  float* part = (float*)(Al + PP * HH);                // 16 MB

  k_prep<<<1, 256, 0, stream>>>(probes, Ah, Al);
  k_scores_mfma<<<dim3(SS / 128, BB), 256, 0, stream>>>(x, Ah, Al, scores);
  k_stats<<<dim3(BB * PP), 256, 0, stream>>>(scores, Mv, invl);
  k_ctx2<<<dim3(16, 4, BB), 256, 0, stream>>>(x, scores, Mv, invl, part);
  k_reduce<<<dim3(BB * PP * HH / 256), 256, 0, stream>>>(part, out);
}

// Round 3
// 484.015 us; speedup vs baseline: 2.7745x; 1.7317x over previous
//
#include <hip/hip_runtime.h>
#include <hip/hip_bf16.h>

#define BB 16
#define SS 8192
#define HH 512
#define PP 32

typedef __attribute__((ext_vector_type(8))) short short8;
typedef __attribute__((ext_vector_type(4))) float f32x4;
typedef __attribute__((ext_vector_type(2))) unsigned int u32x2;

// ---- bf16 split helpers ----------------------------------------------------
__device__ inline unsigned short bf16_hi_trunc(float x) {
  union { float f; unsigned u; } v; v.f = x;
  return (unsigned short)(v.u >> 16);
}
__device__ inline unsigned short bf16_rne(float x) {
  union { float f; unsigned u; } v; v.f = x;
  unsigned r = v.u + 0x7FFFu + ((v.u >> 16) & 1u);
  return (unsigned short)(r >> 16);
}
__device__ inline float from_hi(unsigned short h) {
  union { unsigned u; float f; } v; v.u = ((unsigned)h) << 16;
  return v.f;
}
__device__ inline f32x4 max4(f32x4 a, f32x4 b) {
  f32x4 r; r.x = fmaxf(a.x, b.x); r.y = fmaxf(a.y, b.y);
  r.z = fmaxf(a.z, b.z); r.w = fmaxf(a.w, b.w); return r;
}
__device__ inline f32x4 exp4(f32x4 a) {
  f32x4 r; r.x = __expf(a.x); r.y = __expf(a.y);
  r.z = __expf(a.z); r.w = __expf(a.w); return r;
}
__device__ inline f32x4 fma_b(float a, f32x4 b, f32x4 c) {
  c.x = fmaf(a, b.x, c.x); c.y = fmaf(a, b.y, c.y);
  c.z = fmaf(a, b.z, c.z); c.w = fmaf(a, b.w, c.w); return c;
}

// ---------------------------------------------------------------------------
// K0: pack probes [32][512] f32 into B-fragment layout (hi & lo bf16).
// Slot q = (nt*16 + kcg)*64 + lane holds 8 bf16: probes[nt*16 + (lane&15)]
//                                               [kcg*32 + (lane>>4)*8 + j]
// ---------------------------------------------------------------------------
__global__ void k_prep(const float* __restrict__ probes,
                       short* __restrict__ Ph, short* __restrict__ Pl) {
  int t = threadIdx.x;
  for (int q = t; q < 2048; q += 256) {
    int lane = q & 63, kcg = (q >> 6) & 15, nt = q >> 10;
    int p = nt * 16 + (lane & 15);
    int h0 = kcg * 32 + (lane >> 4) * 8;
#pragma unroll
    for (int j = 0; j < 8; ++j) {
      float f = probes[p * HH + h0 + j];
      unsigned short h = bf16_hi_trunc(f);
      Ph[q * 8 + j] = (short)h;
      Pl[q * 8 + j] = (short)bf16_rne(f - from_hi(h));
    }
  }
}

// ---------------------------------------------------------------------------
// K1: scoresT[b][s][p] = x[b][s][:] . probes[p][:]  (split-bf16 MFMA, x = A)
// grid (S/64, B), block 256 = 4 waves; wave w = m-tile rows w*16..+16.
// x staged f32->bf16(hi,lo) in XOR-swizzled LDS (16B granules); probes frags
// L2-hot from ws. 3-term product: xh*ph + xh*pl + xl*ph.
// ---------------------------------------------------------------------------
__global__ __launch_bounds__(256) void k_scores3(
    const float* __restrict__ x, const short* __restrict__ Ph,
    const short* __restrict__ Pl, float* __restrict__ scoresT) {
  __shared__ __align__(16) short Bh[64 * 128];  // 16 KB (64 s x 128 h bf16)
  __shared__ __align__(16) short Bl[64 * 128];  // 16 KB
  const int t = threadIdx.x;
  const int lane = t & 63, w = t >> 6;
  const int b = blockIdx.y;
  const int stile = blockIdx.x;  // 64-row s tile

  f32x4 acc[2];
  acc[0] = (f32x4){0.f, 0.f, 0.f, 0.f};
  acc[1] = (f32x4){0.f, 0.f, 0.f, 0.f};

  const int frow = w * 16 + (lane & 15);  // A-frag row (s within tile)
  const int g4 = lane >> 4;

  for (int hc = 0; hc < 4; ++hc) {  // 128-h chunks
    if (hc) __syncthreads();
    // ---- stage: coalesced f32x4 loads, convert, swizzled ds_write_b64 ----
#pragma unroll
    for (int it = 0; it < 8; ++it) {
      int g = t + 256 * it;  // 0..2047 : row = g>>5, u = g&31 (4-float unit)
      int row = g >> 5, u = g & 31;
      f32x4 v = *(const f32x4*)(x + ((size_t)b * SS + stile * 64 + row) * HH +
                                hc * 128 + u * 4);
      unsigned short h0 = bf16_hi_trunc(v.x), h1 = bf16_hi_trunc(v.y);
      unsigned short h2 = bf16_hi_trunc(v.z), h3 = bf16_hi_trunc(v.w);
      u32x2 hi, lo;
      hi.x = (unsigned)h0 | ((unsigned)h1 << 16);
      hi.y = (unsigned)h2 | ((unsigned)h3 << 16);
      lo.x = (unsigned)bf16_rne(v.x - from_hi(h0)) |
             ((unsigned)bf16_rne(v.y - from_hi(h1)) << 16);
      lo.y = (unsigned)bf16_rne(v.z - from_hi(h2)) |
             ((unsigned)bf16_rne(v.w - from_hi(h3)) << 16);
      int qsw = ((u >> 1) ^ (row & 15));
      int idx = row * 128 + qsw * 8 + (u & 1) * 4;
      *(u32x2*)&Bh[idx] = hi;
      *(u32x2*)&Bl[idx] = lo;
    }
    __syncthreads();

    // ---- compute: 4 kc x 2 nt x 3 mfma ----
#pragma unroll
    for (int kc = 0; kc < 4; ++kc) {
      int qr = ((kc * 4 + g4) ^ (frow & 15));
      short8 xh = *(const short8*)&Bh[frow * 128 + qr * 8];
      short8 xl = *(const short8*)&Bl[frow * 128 + qr * 8];
      int kcg = hc * 4 + kc;
#pragma unroll
      for (int nt = 0; nt < 2; ++nt) {
        short8 ph = *(const short8*)(Ph + ((size_t)((nt * 16 + kcg) * 64 + lane)) * 8);
        short8 pl = *(const short8*)(Pl + ((size_t)((nt * 16 + kcg) * 64 + lane)) * 8);
        acc[nt] = __builtin_amdgcn_mfma_f32_16x16x32_bf16(xh, ph, acc[nt], 0, 0, 0);
        acc[nt] = __builtin_amdgcn_mfma_f32_16x16x32_bf16(xh, pl, acc[nt], 0, 0, 0);
        acc[nt] = __builtin_amdgcn_mfma_f32_16x16x32_bf16(xl, ph, acc[nt], 0, 0, 0);
      }
    }
  }

  // C/D: col(lane&15) = p (B dim), row = (lane>>4)*4 + r = s-within-m-tile
#pragma unroll
  for (int nt = 0; nt < 2; ++nt)
#pragma unroll
    for (int r = 0; r < 4; ++r) {
      int s = stile * 64 + w * 16 + (lane >> 4) * 4 + r;
      int p = nt * 16 + (lane & 15);
      scoresT[((size_t)b * SS + s) * PP + p] = acc[nt][r];
    }
}

// ---------------------------------------------------------------------------
// K2a: partial (max, sumexp) per (b,p) over 1024-s ranges. grid 128.
// ---------------------------------------------------------------------------
__global__ __launch_bounds__(256) void k_stats_a(
    const float* __restrict__ scoresT, float* __restrict__ pm,
    float* __restrict__ pl_) {
  const int blk = blockIdx.x;  // b*8 + sr
  const int b = blk >> 3, sr = blk & 7;
  const int t = threadIdx.x;
  const int p4 = t & 7, sg = t >> 3;
  const f32x4* base = (const f32x4*)(scoresT + ((size_t)b * SS + sr * 1024) * PP);

  f32x4 m4 = (f32x4){-1e30f, -1e30f, -1e30f, -1e30f};
  f32x4 l4 = (f32x4){0.f, 0.f, 0.f, 0.f};
#pragma unroll 4
  for (int i = 0; i < 32; ++i) {
    int s = sg + 32 * i;
    f32x4 v = base[s * 8 + p4];
    f32x4 nm = max4(m4, v);
    l4 = l4 * exp4(m4 - nm) + exp4(v - nm);
    m4 = nm;
  }
  __shared__ f32x4 sm[32][8], sl[32][8];
  sm[sg][p4] = m4;
  sl[sg][p4] = l4;
  __syncthreads();
  if (t < 8) {
    f32x4 M = sm[0][t], L = sl[0][t];
#pragma unroll 4
    for (int i = 1; i < 32; ++i) {
      f32x4 m2 = sm[i][t], l2 = sl[i][t];
      f32x4 nm = max4(M, m2);
      L = L * exp4(M - nm) + l2 * exp4(m2 - nm);
      M = nm;
    }
    *(f32x4*)&pm[blk * PP + t * 4] = M;
    *(f32x4*)&pl_[blk * PP + t * 4] = L;
  }
}

// ---------------------------------------------------------------------------
// K2b: merge 8 partials -> Mv, invl per (b,p)
// ---------------------------------------------------------------------------
__global__ __launch_bounds__(256) void k_stats_b(
    const float* __restrict__ pm, const float* __restrict__ pl_,
    float* __restrict__ Mv, float* __restrict__ invl) {
  int i = blockIdx.x * 256 + threadIdx.x;
  if (i >= BB * PP) return;
  int b = i >> 5, p = i & 31;
  float M = -1e30f, L = 0.f;
#pragma unroll
  for (int sr = 0; sr < 8; ++sr) {
    float m2 = pm[(b * 8 + sr) * PP + p], l2 = pl_[(b * 8 + sr) * PP + p];
    float nm = fmaxf(M, m2);
    L = L * __expf(M - nm) + l2 * __expf(m2 - nm);
    M = nm;
  }
  Mv[i] = M;
  invl[i] = 1.0f / L;
}

// ---------------------------------------------------------------------------
// K3: partial ctx over 512-s chunk & 256-h half. grid (16, 2, B), block 256.
// Lane owns h-float4 (1 KB unique per wave-instr); wave w owns p in [8w,8w+8).
// Softmax weights for the whole chunk staged once in 64 KB LDS (1 barrier);
// per-j weight reads are same-address broadcasts (free).
// ---------------------------------------------------------------------------
__global__ __launch_bounds__(256) void k_ctx3(
    const float* __restrict__ x, const float* __restrict__ scoresT,
    const float* __restrict__ Mv, const float* __restrict__ invl,
    float* __restrict__ part) {
  __shared__ float wl[512 * PP];  // 64 KB
  const int t = threadIdx.x;
  const int lane = t & 63, w = t >> 6;
  const int sc = blockIdx.x, hh = blockIdx.y, b = blockIdx.z;

  // ---- stage softmax weights (coalesced, then contiguous b128 writes) ----
  const int pbase = (4 * t) & 31;
  f32x4 mv = *(const f32x4*)(Mv + b * PP + pbase);
  f32x4 il = *(const f32x4*)(invl + b * PP + pbase);
  const f32x4* src = (const f32x4*)(scoresT + ((size_t)b * SS + sc * 512) * PP);
#pragma unroll
  for (int it = 0; it < 16; ++it) {
    f32x4 v = src[t + 256 * it];
    f32x4 e;
    e.x = __expf(v.x - mv.x) * il.x;
    e.y = __expf(v.y - mv.y) * il.y;
    e.z = __expf(v.z - mv.z) * il.z;
    e.w = __expf(v.w - mv.w) * il.w;
    *(f32x4*)&wl[(t + 256 * it) * 4] = e;
  }
  __syncthreads();

  const float* xrow = x + ((size_t)b * SS + sc * 512) * HH + hh * 256 + lane * 4;
  const f32x4* wj = (const f32x4*)wl;

  f32x4 acc[8];
#pragma unroll
  for (int k = 0; k < 8; ++k) acc[k] = (f32x4){0.f, 0.f, 0.f, 0.f};

#pragma unroll 4
  for (int j = 0; j < 512; ++j) {
    f32x4 xv = *(const f32x4*)(xrow + (size_t)j * HH);
    f32x4 w0 = wj[j * 8 + w * 2];      // w[j][8w .. 8w+4)  broadcast
    f32x4 w1 = wj[j * 8 + w * 2 + 1];  // w[j][8w+4 .. 8w+8)
    acc[0] = fma_b(w0.x, xv, acc[0]);
    acc[1] = fma_b(w0.y, xv, acc[1]);
    acc[2] = fma_b(w0.z, xv, acc[2]);
    acc[3] = fma_b(w0.w, xv, acc[3]);
    acc[4] = fma_b(w1.x, xv, acc[4]);
    acc[5] = fma_b(w1.y, xv, acc[5]);
    acc[6] = fma_b(w1.z, xv, acc[6]);
    acc[7] = fma_b(w1.w, xv, acc[7]);
  }

#pragma unroll
  for (int pi = 0; pi < 8; ++pi) {
    int p = w * 8 + pi;
    *(f32x4*)(part + (((size_t)sc * BB + b) * PP + p) * HH + hh * 256 + lane * 4) =
        acc[pi];
  }
}

// ---------------------------------------------------------------------------
// K4: out = sum over 16 s-chunk partials
// ---------------------------------------------------------------------------
__global__ __launch_bounds__(256) void k_reduce(const float* __restrict__ part,
                                               float* __restrict__ out) {
  int i = blockIdx.x * 256 + threadIdx.x;
  float s = 0.f;
#pragma unroll
  for (int c = 0; c < 16; ++c) s += part[(size_t)c * (BB * PP * HH) + i];
  out[i] = s;
}

extern "C" void kernel_launch(void* const* d_in, const int* in_sizes, int n_in,
                              void* d_out, int out_size, void* d_ws, size_t ws_size,
                              hipStream_t stream) {
  const float* x = (const float*)d_in[0];       // [B,S,H] f32
  const float* probes = (const float*)d_in[1];  // [P,H]  f32
  float* out = (float*)d_out;                   // [B,P*H] f32

  float* scoresT = (float*)d_ws;                        // B*S*P = 16.8 MB
  float* part = scoresT + (size_t)BB * SS * PP;         // 16*B*P*H = 16.8 MB
  float* Mv = part + (size_t)16 * BB * PP * HH;         // 512
  float* invl = Mv + BB * PP;                           // 512
  float* pm = invl + BB * PP;                           // 4096
  float* pl_ = pm + 128 * PP;                           // 4096
  short* Ph = (short*)(pl_ + 128 * PP);                 // 32 KB
  short* Pl = Ph + PP * HH;                             // 32 KB

  k_prep<<<1, 256, 0, stream>>>(probes, Ph, Pl);
  k_scores3<<<dim3(SS / 64, BB), 256, 0, stream>>>(x, Ph, Pl, scoresT);
  k_stats_a<<<dim3(128), 256, 0, stream>>>(scoresT, pm, pl_);
  k_stats_b<<<dim3(2), 256, 0, stream>>>(pm, pl_, Mv, invl);
  k_ctx3<<<dim3(16, 2, BB), 256, 0, stream>>>(x, scoresT, Mv, invl, part);
  k_reduce<<<dim3(BB * PP * HH / 256), 256, 0, stream>>>(part, out);
}

// Round 4
// 472.134 us; speedup vs baseline: 2.8444x; 1.0252x over previous
//
#include <hip/hip_runtime.h>
#include <hip/hip_bf16.h>

#define BB 16
#define SS 8192
#define HH 512
#define PP 32

typedef __attribute__((ext_vector_type(8))) short short8;
typedef __attribute__((ext_vector_type(4))) float f32x4;

// ---- bf16 split helpers ----------------------------------------------------
__device__ inline unsigned short bf16_hi_trunc(float x) {
  union { float f; unsigned u; } v; v.f = x;
  return (unsigned short)(v.u >> 16);
}
__device__ inline unsigned short bf16_rne(float x) {
  union { float f; unsigned u; } v; v.f = x;
  unsigned r = v.u + 0x7FFFu + ((v.u >> 16) & 1u);
  return (unsigned short)(r >> 16);
}
__device__ inline float from_hi(unsigned short h) {
  union { unsigned u; float f; } v; v.u = ((unsigned)h) << 16;
  return v.f;
}
__device__ inline f32x4 max4(f32x4 a, f32x4 b) {
  f32x4 r; r.x = fmaxf(a.x, b.x); r.y = fmaxf(a.y, b.y);
  r.z = fmaxf(a.z, b.z); r.w = fmaxf(a.w, b.w); return r;
}
__device__ inline f32x4 exp4(f32x4 a) {
  f32x4 r; r.x = __expf(a.x); r.y = __expf(a.y);
  r.z = __expf(a.z); r.w = __expf(a.w); return r;
}
__device__ inline f32x4 fma_b(float a, f32x4 b, f32x4 c) {
  c.x = fmaf(a, b.x, c.x); c.y = fmaf(a, b.y, c.y);
  c.z = fmaf(a, b.z, c.z); c.w = fmaf(a, b.w, c.w); return c;
}
// convert 8 f32 -> hi/lo bf16 short8
__device__ inline void cvt8(const float* xv, short8& bh, short8& bl) {
#pragma unroll
  for (int j = 0; j < 8; ++j) {
    unsigned short h = bf16_hi_trunc(xv[j]);
    bh[j] = (short)h;
    bl[j] = (short)bf16_rne(xv[j] - from_hi(h));
  }
}

// ---------------------------------------------------------------------------
// K0: pack probes [32][512] f32 into B-fragment layout (hi & lo bf16).
// Slot q = (nt*16 + kcg)*64 + lane holds 8 bf16: probes[nt*16 + (lane&15)]
//                                               [kcg*32 + (lane>>4)*8 + j]
// ---------------------------------------------------------------------------
__global__ void k_prep(const float* __restrict__ probes,
                       short* __restrict__ Ph, short* __restrict__ Pl) {
  int t = threadIdx.x;
  for (int q = t; q < 2048; q += 256) {
    int lane = q & 63, kcg = (q >> 6) & 15, nt = q >> 10;
    int p = nt * 16 + (lane & 15);
    int h0 = kcg * 32 + (lane >> 4) * 8;
#pragma unroll
    for (int j = 0; j < 8; ++j) {
      float f = probes[p * HH + h0 + j];
      unsigned short h = bf16_hi_trunc(f);
      Ph[q * 8 + j] = (short)h;
      Pl[q * 8 + j] = (short)bf16_rne(f - from_hi(h));
    }
  }
}

// ---------------------------------------------------------------------------
// K1: scoresT[b][s][p] = x[b][s][:].probes[p][:]  — split-bf16 MFMA, NO LDS.
// grid (S/64, B), block 256 = 4 waves; wave w owns s-rows w*16..+16 (A m-tile).
// A-frags load straight from global f32 (each 128B line consumed exactly once
// by one wave: lanes {l,l+16,l+32,l+48} cover 4x32B of a row) and convert
// in-register. Probe B-frags stream from L2-hot packed ws.
// ---------------------------------------------------------------------------
__global__ __launch_bounds__(256) void k_scores4(
    const float* __restrict__ x, const short* __restrict__ Ph,
    const short* __restrict__ Pl, float* __restrict__ scoresT) {
  const int t = threadIdx.x;
  const int lane = t & 63, w = t >> 6;
  const int b = blockIdx.y;
  const int stile = blockIdx.x;  // 64-row s tile

  f32x4 acc[2];
  acc[0] = (f32x4){0.f, 0.f, 0.f, 0.f};
  acc[1] = (f32x4){0.f, 0.f, 0.f, 0.f};

  const int srow = stile * 64 + w * 16 + (lane & 15);
  const float* xr = x + ((size_t)b * SS + srow) * HH + (lane >> 4) * 8;

#pragma unroll 2
  for (int kcg = 0; kcg < 16; ++kcg) {
    // A-frag: 8 f32 from global, convert to hi/lo bf16
    f32x4 xa = *(const f32x4*)(xr + kcg * 32);
    f32x4 xc = *(const f32x4*)(xr + kcg * 32 + 4);
    float xv[8] = {xa.x, xa.y, xa.z, xa.w, xc.x, xc.y, xc.z, xc.w};
    short8 xh, xl;
    cvt8(xv, xh, xl);
    // B-frags (probes) from L2
    short8 ph0 = *(const short8*)(Ph + ((size_t)(kcg * 64 + lane)) * 8);
    short8 pl0 = *(const short8*)(Pl + ((size_t)(kcg * 64 + lane)) * 8);
    short8 ph1 = *(const short8*)(Ph + ((size_t)((16 + kcg) * 64 + lane)) * 8);
    short8 pl1 = *(const short8*)(Pl + ((size_t)((16 + kcg) * 64 + lane)) * 8);
    acc[0] = __builtin_amdgcn_mfma_f32_16x16x32_bf16(xh, ph0, acc[0], 0, 0, 0);
    acc[0] = __builtin_amdgcn_mfma_f32_16x16x32_bf16(xh, pl0, acc[0], 0, 0, 0);
    acc[0] = __builtin_amdgcn_mfma_f32_16x16x32_bf16(xl, ph0, acc[0], 0, 0, 0);
    acc[1] = __builtin_amdgcn_mfma_f32_16x16x32_bf16(xh, ph1, acc[1], 0, 0, 0);
    acc[1] = __builtin_amdgcn_mfma_f32_16x16x32_bf16(xh, pl1, acc[1], 0, 0, 0);
    acc[1] = __builtin_amdgcn_mfma_f32_16x16x32_bf16(xl, ph1, acc[1], 0, 0, 0);
  }

  // C/D: col(lane&15) = p, row = (lane>>4)*4 + r = s-within-m-tile
#pragma unroll
  for (int nt = 0; nt < 2; ++nt)
#pragma unroll
    for (int r = 0; r < 4; ++r) {
      int s = stile * 64 + w * 16 + (lane >> 4) * 4 + r;
      int p = nt * 16 + (lane & 15);
      scoresT[((size_t)b * SS + s) * PP + p] = acc[nt][r];
    }
}

// ---------------------------------------------------------------------------
// K2a: partial (max, sumexp) per (b,p) over 256-s ranges. grid 512.
// ---------------------------------------------------------------------------
__global__ __launch_bounds__(256) void k_stats_a(
    const float* __restrict__ scoresT, float* __restrict__ pm,
    float* __restrict__ pl_) {
  const int blk = blockIdx.x;  // b*32 + sr
  const int b = blk >> 5, sr = blk & 31;
  const int t = threadIdx.x;
  const int p4 = t & 7, sg = t >> 3;
  const f32x4* base = (const f32x4*)(scoresT + ((size_t)b * SS + sr * 256) * PP);

  f32x4 m4 = (f32x4){-1e30f, -1e30f, -1e30f, -1e30f};
  f32x4 l4 = (f32x4){0.f, 0.f, 0.f, 0.f};
#pragma unroll
  for (int i = 0; i < 8; ++i) {
    int s = sg + 32 * i;
    f32x4 v = base[s * 8 + p4];
    f32x4 nm = max4(m4, v);
    l4 = l4 * exp4(m4 - nm) + exp4(v - nm);
    m4 = nm;
  }
  __shared__ f32x4 sm[32][8], sl[32][8];
  sm[sg][p4] = m4;
  sl[sg][p4] = l4;
  __syncthreads();
  if (t < 8) {
    f32x4 M = sm[0][t], L = sl[0][t];
#pragma unroll
    for (int i = 1; i < 32; ++i) {
      f32x4 m2 = sm[i][t], l2 = sl[i][t];
      f32x4 nm = max4(M, m2);
      L = L * exp4(M - nm) + l2 * exp4(m2 - nm);
      M = nm;
    }
    *(f32x4*)&pm[blk * PP + t * 4] = M;
    *(f32x4*)&pl_[blk * PP + t * 4] = L;
  }
}

// ---------------------------------------------------------------------------
// K2b: merge 32 partials -> Mv, invl per (b,p)
// ---------------------------------------------------------------------------
__global__ __launch_bounds__(256) void k_stats_b(
    const float* __restrict__ pm, const float* __restrict__ pl_,
    float* __restrict__ Mv, float* __restrict__ invl) {
  int i = blockIdx.x * 256 + threadIdx.x;
  if (i >= BB * PP) return;
  int b = i >> 5, p = i & 31;
  float M = -1e30f, L = 0.f;
#pragma unroll
  for (int sr = 0; sr < 32; ++sr) {
    float m2 = pm[(b * 32 + sr) * PP + p], l2 = pl_[(b * 32 + sr) * PP + p];
    float nm = fmaxf(M, m2);
    L = L * __expf(M - nm) + l2 * __expf(m2 - nm);
    M = nm;
  }
  Mv[i] = M;
  invl[i] = 1.0f / L;
}

// ---------------------------------------------------------------------------
// K3: partial ctx over 256-s chunk & 256-h half. grid (32, 2, B) = 1024
// blocks (4/CU), block 256. Lane owns h-float4 (1 KB unique per wave-instr);
// wave w owns p in [8w,8w+8). Weights staged once in 32 KB LDS (1 barrier);
// j-loop unrolled x8 with batched loads for latency hiding.
// ---------------------------------------------------------------------------
__global__ __launch_bounds__(256) void k_ctx4(
    const float* __restrict__ x, const float* __restrict__ scoresT,
    const float* __restrict__ Mv, const float* __restrict__ invl,
    float* __restrict__ part) {
  __shared__ float wl[256 * PP];  // 32 KB
  const int t = threadIdx.x;
  const int lane = t & 63, w = t >> 6;
  const int sc = blockIdx.x, hh = blockIdx.y, b = blockIdx.z;

  // ---- stage softmax weights (coalesced reads, contiguous b128 writes) ----
  const int pbase = (4 * t) & 31;
  f32x4 mv = *(const f32x4*)(Mv + b * PP + pbase);
  f32x4 il = *(const f32x4*)(invl + b * PP + pbase);
  const f32x4* src = (const f32x4*)(scoresT + ((size_t)b * SS + sc * 256) * PP);
#pragma unroll
  for (int it = 0; it < 8; ++it) {
    f32x4 v = src[t + 256 * it];
    f32x4 e;
    e.x = __expf(v.x - mv.x) * il.x;
    e.y = __expf(v.y - mv.y) * il.y;
    e.z = __expf(v.z - mv.z) * il.z;
    e.w = __expf(v.w - mv.w) * il.w;
    *(f32x4*)&wl[(t + 256 * it) * 4] = e;
  }
  __syncthreads();

  const float* xrow = x + ((size_t)b * SS + sc * 256) * HH + hh * 256 + lane * 4;
  const f32x4* wj = (const f32x4*)wl;

  f32x4 acc[8];
#pragma unroll
  for (int k = 0; k < 8; ++k) acc[k] = (f32x4){0.f, 0.f, 0.f, 0.f};

  for (int jo = 0; jo < 256; jo += 8) {
    f32x4 xv[8];
#pragma unroll
    for (int u = 0; u < 8; ++u)
      xv[u] = *(const f32x4*)(xrow + (size_t)(jo + u) * HH);
#pragma unroll
    for (int u = 0; u < 8; ++u) {
      int j = jo + u;
      f32x4 w0 = wj[j * 8 + w * 2];      // w[j][8w..8w+4)   broadcast
      f32x4 w1 = wj[j * 8 + w * 2 + 1];  // w[j][8w+4..8w+8) broadcast
      acc[0] = fma_b(w0.x, xv[u], acc[0]);
      acc[1] = fma_b(w0.y, xv[u], acc[1]);
      acc[2] = fma_b(w0.z, xv[u], acc[2]);
      acc[3] = fma_b(w0.w, xv[u], acc[3]);
      acc[4] = fma_b(w1.x, xv[u], acc[4]);
      acc[5] = fma_b(w1.y, xv[u], acc[5]);
      acc[6] = fma_b(w1.z, xv[u], acc[6]);
      acc[7] = fma_b(w1.w, xv[u], acc[7]);
    }
  }

#pragma unroll
  for (int pi = 0; pi < 8; ++pi) {
    int p = w * 8 + pi;
    *(f32x4*)(part + (((size_t)sc * BB + b) * PP + p) * HH + hh * 256 + lane * 4) =
        acc[pi];
  }
}

// ---------------------------------------------------------------------------
// K4: out = sum over 32 s-chunk partials
// ---------------------------------------------------------------------------
__global__ __launch_bounds__(256) void k_reduce(const float* __restrict__ part,
                                               float* __restrict__ out) {
  int i = blockIdx.x * 256 + threadIdx.x;
  float s = 0.f;
#pragma unroll
  for (int c = 0; c < 32; ++c) s += part[(size_t)c * (BB * PP * HH) + i];
  out[i] = s;
}

extern "C" void kernel_launch(void* const* d_in, const int* in_sizes, int n_in,
                              void* d_out, int out_size, void* d_ws, size_t ws_size,
                              hipStream_t stream) {
  const float* x = (const float*)d_in[0];       // [B,S,H] f32
  const float* probes = (const float*)d_in[1];  // [P,H]  f32
  float* out = (float*)d_out;                   // [B,P*H] f32

  float* scoresT = (float*)d_ws;                        // B*S*P = 16.8 MB
  float* part = scoresT + (size_t)BB * SS * PP;         // 32*B*P*H = 33.6 MB
  float* Mv = part + (size_t)32 * BB * PP * HH;         // 512
  float* invl = Mv + BB * PP;                           // 512
  float* pm = invl + BB * PP;                           // 16384
  float* pl_ = pm + 512 * PP;                           // 16384
  short* Ph = (short*)(pl_ + 512 * PP);                 // 32 KB
  short* Pl = Ph + PP * HH;                             // 32 KB

  k_prep<<<1, 256, 0, stream>>>(probes, Ph, Pl);
  k_scores4<<<dim3(SS / 64, BB), 256, 0, stream>>>(x, Ph, Pl, scoresT);
  k_stats_a<<<dim3(512), 256, 0, stream>>>(scoresT, pm, pl_);
  k_stats_b<<<dim3(2), 256, 0, stream>>>(pm, pl_, Mv, invl);
  k_ctx4<<<dim3(32, 2, BB), 256, 0, stream>>>(x, scoresT, Mv, invl, part);
  k_reduce<<<dim3(BB * PP * HH / 256), 256, 0, stream>>>(part, out);
}